// Round 2
// baseline (374.821 us; speedup 1.0000x reference)
//
#include <hip/hip_runtime.h>

#define N_NODES 40000
#define N_EDGES 640000
// IN_CH = HID_CH = 128, OUT_CH = 64

constexpr int BM = 128;        // node tile (GEMM)
constexpr int BK = 16;         // k tile
constexpr int LDSW = BM + 4;   // padded LDS row stride (floats)

// ================= CSR build =================
// deg[dst]++ per edge
__global__ __launch_bounds__(256) void k_count(
    const int* __restrict__ ei, int* __restrict__ deg) {
  int e = blockIdx.x * 256 + threadIdx.x;   // grid covers exactly N_EDGES
  atomicAdd(&deg[ei[N_EDGES + e]], 1);
}

// exclusive scan of deg[0..N_NODES) -> offs, cursor (single block, 1024 thr)
__global__ __launch_bounds__(1024) void k_scan(
    const int* __restrict__ deg, int* __restrict__ offs,
    int* __restrict__ cursor) {
  __shared__ int sbuf[1024];
  __shared__ int scarry;
  const int t = threadIdx.x;
  if (t == 0) scarry = 0;
  __syncthreads();
  for (int base = 0; base < N_NODES; base += 1024) {
    int i = base + t;
    int v = (i < N_NODES) ? deg[i] : 0;
    sbuf[t] = v;
    __syncthreads();
#pragma unroll
    for (int off = 1; off < 1024; off <<= 1) {
      int y = (t >= off) ? sbuf[t - off] : 0;
      __syncthreads();
      if (t >= off) sbuf[t] += y;
      __syncthreads();
    }
    int excl = sbuf[t] - v;
    int c = scarry;
    if (i < N_NODES) {
      offs[i] = c + excl;
      cursor[i] = c + excl;
    }
    __syncthreads();
    if (t == 0) scarry = c + sbuf[1023];
    __syncthreads();
  }
  if (t == 0) offs[N_NODES] = scarry;   // == N_EDGES
}

// csr_src[cursor[dst]++] = src  (order within a node irrelevant for sum)
__global__ __launch_bounds__(256) void k_fill(
    const int* __restrict__ ei, int* __restrict__ cursor,
    int* __restrict__ csr_src) {
  int e = blockIdx.x * 256 + threadIdx.x;
  int dst = ei[N_EDGES + e];
  int idx = atomicAdd(&cursor[dst], 1);
  csr_src[idx] = ei[e];
}

// ================= gather aggregation =================
// one wave64 per node, 2 ch/lane: agg[n] = sum_{j->n} x[j]  (128 ch)
__global__ __launch_bounds__(256) void k_gather128(
    const float* __restrict__ x, const int* __restrict__ csr_src,
    const int* __restrict__ offs, float* __restrict__ agg) {
  int n = blockIdx.x * 4 + (threadIdx.x >> 6);
  n = __builtin_amdgcn_readfirstlane(n);   // wave-uniform -> scalar loads
  const int lane = threadIdx.x & 63;
  const int s = offs[n], e = offs[n + 1];
  float2 a0 = make_float2(0.f, 0.f), a1 = a0;
  int i = s;
  for (; i + 1 < e; i += 2) {
    int s0 = csr_src[i], s1 = csr_src[i + 1];
    float2 v0 = *reinterpret_cast<const float2*>(x + (size_t)s0 * 128 + lane * 2);
    float2 v1 = *reinterpret_cast<const float2*>(x + (size_t)s1 * 128 + lane * 2);
    a0.x += v0.x; a0.y += v0.y;
    a1.x += v1.x; a1.y += v1.y;
  }
  if (i < e) {
    int s0 = csr_src[i];
    float2 v0 = *reinterpret_cast<const float2*>(x + (size_t)s0 * 128 + lane * 2);
    a0.x += v0.x; a0.y += v0.y;
  }
  float2 r = make_float2(a0.x + a1.x, a0.y + a1.y);
  *reinterpret_cast<float2*>(agg + (size_t)n * 128 + lane * 2) = r;
}

// one wave64 per node, 1 ch/lane: out[n] += sum_{j->n} t2[j]  (64 ch)
__global__ __launch_bounds__(256) void k_gather64(
    const float* __restrict__ t2, const int* __restrict__ csr_src,
    const int* __restrict__ offs, float* __restrict__ out) {
  int n = blockIdx.x * 4 + (threadIdx.x >> 6);
  n = __builtin_amdgcn_readfirstlane(n);
  const int lane = threadIdx.x & 63;
  const int s = offs[n], e = offs[n + 1];
  float a0 = 0.f, a1 = 0.f;
  int i = s;
  for (; i + 1 < e; i += 2) {
    int s0 = csr_src[i], s1 = csr_src[i + 1];
    a0 += t2[(size_t)s0 * 64 + lane];
    a1 += t2[(size_t)s1 * 64 + lane];
  }
  if (i < e) a0 += t2[(size_t)csr_src[i] * 64 + lane];
  out[(size_t)n * 64 + lane] += a0 + a1;
}

// ---------------- GEMM1: h = relu(agg @ W1rel.T + x @ W1root.T + b1) ----
__global__ __launch_bounds__(256) void k_gemm1(
    const float* __restrict__ agg, const float* __restrict__ x,
    const float* __restrict__ Wrel, const float* __restrict__ Wroot,
    const float* __restrict__ bias, float* __restrict__ h) {
  __shared__ float sAg[BK * LDSW];
  __shared__ float sAx[BK * LDSW];
  __shared__ float sWr[BK * LDSW];
  __shared__ float sWo[BK * LDSW];

  const int t = threadIdx.x;
  const int n0 = blockIdx.x * BM;
  const int tn = (t >> 4) << 3;   // node offset within tile
  const int to = (t & 15) << 3;   // out-channel offset

  float acc[8][8];
#pragma unroll
  for (int i = 0; i < 8; ++i)
#pragma unroll
    for (int j = 0; j < 8; ++j) acc[i][j] = 0.f;

  float bv[8];
  *reinterpret_cast<float4*>(&bv[0]) = *reinterpret_cast<const float4*>(bias + to);
  *reinterpret_cast<float4*>(&bv[4]) = *reinterpret_cast<const float4*>(bias + to + 4);

  const int lc = (t & 3) << 2;
  const int lr = t >> 2;

  for (int kk = 0; kk < 128; kk += BK) {
    __syncthreads();
#pragma unroll
    for (int p = 0; p < 2; ++p) {
      int rr = lr + p * 64;
      int row = n0 + rr;
      float4 va = make_float4(0.f, 0.f, 0.f, 0.f);
      float4 vx = va;
      if (row < N_NODES) {
        va = *reinterpret_cast<const float4*>(agg + (size_t)row * 128 + kk + lc);
        vx = *reinterpret_cast<const float4*>(x + (size_t)row * 128 + kk + lc);
      }
      float4 vr = *reinterpret_cast<const float4*>(Wrel + (size_t)rr * 128 + kk + lc);
      float4 vo = *reinterpret_cast<const float4*>(Wroot + (size_t)rr * 128 + kk + lc);
      sAg[(lc + 0) * LDSW + rr] = va.x;
      sAg[(lc + 1) * LDSW + rr] = va.y;
      sAg[(lc + 2) * LDSW + rr] = va.z;
      sAg[(lc + 3) * LDSW + rr] = va.w;
      sAx[(lc + 0) * LDSW + rr] = vx.x;
      sAx[(lc + 1) * LDSW + rr] = vx.y;
      sAx[(lc + 2) * LDSW + rr] = vx.z;
      sAx[(lc + 3) * LDSW + rr] = vx.w;
      sWr[(lc + 0) * LDSW + rr] = vr.x;
      sWr[(lc + 1) * LDSW + rr] = vr.y;
      sWr[(lc + 2) * LDSW + rr] = vr.z;
      sWr[(lc + 3) * LDSW + rr] = vr.w;
      sWo[(lc + 0) * LDSW + rr] = vo.x;
      sWo[(lc + 1) * LDSW + rr] = vo.y;
      sWo[(lc + 2) * LDSW + rr] = vo.z;
      sWo[(lc + 3) * LDSW + rr] = vo.w;
    }
    __syncthreads();
#pragma unroll
    for (int k = 0; k < BK; ++k) {
      float av[8], cv[8], rv[8], ov[8];
      *reinterpret_cast<float4*>(&av[0]) = *reinterpret_cast<const float4*>(&sAg[k * LDSW + tn]);
      *reinterpret_cast<float4*>(&av[4]) = *reinterpret_cast<const float4*>(&sAg[k * LDSW + tn + 4]);
      *reinterpret_cast<float4*>(&cv[0]) = *reinterpret_cast<const float4*>(&sAx[k * LDSW + tn]);
      *reinterpret_cast<float4*>(&cv[4]) = *reinterpret_cast<const float4*>(&sAx[k * LDSW + tn + 4]);
      *reinterpret_cast<float4*>(&rv[0]) = *reinterpret_cast<const float4*>(&sWr[k * LDSW + to]);
      *reinterpret_cast<float4*>(&rv[4]) = *reinterpret_cast<const float4*>(&sWr[k * LDSW + to + 4]);
      *reinterpret_cast<float4*>(&ov[0]) = *reinterpret_cast<const float4*>(&sWo[k * LDSW + to]);
      *reinterpret_cast<float4*>(&ov[4]) = *reinterpret_cast<const float4*>(&sWo[k * LDSW + to + 4]);
#pragma unroll
      for (int i = 0; i < 8; ++i)
#pragma unroll
        for (int j = 0; j < 8; ++j)
          acc[i][j] = fmaf(av[i], rv[j], fmaf(cv[i], ov[j], acc[i][j]));
    }
  }

#pragma unroll
  for (int i = 0; i < 8; ++i) {
    int row = n0 + tn + i;
    if (row < N_NODES) {
#pragma unroll
      for (int j = 0; j < 8; j += 4) {
        float4 o;
        o.x = fmaxf(acc[i][j + 0] + bv[j + 0], 0.f);
        o.y = fmaxf(acc[i][j + 1] + bv[j + 1], 0.f);
        o.z = fmaxf(acc[i][j + 2] + bv[j + 2], 0.f);
        o.w = fmaxf(acc[i][j + 3] + bv[j + 3], 0.f);
        *reinterpret_cast<float4*>(h + (size_t)row * 128 + to + j) = o;
      }
    }
  }
}

// ---------------- GEMM2: [t2 | out_init] = h @ [W2rel ; W2root].T (+b2) --
__global__ __launch_bounds__(256) void k_gemm2(
    const float* __restrict__ h, const float* __restrict__ Wrel,
    const float* __restrict__ Wroot, const float* __restrict__ bias,
    float* __restrict__ t2, float* __restrict__ out) {
  __shared__ float sA[BK * LDSW];
  __shared__ float sW[BK * LDSW];

  const int t = threadIdx.x;
  const int n0 = blockIdx.x * BM;
  const int tn = (t >> 4) << 3;
  const int to = (t & 15) << 3;

  float acc[8][8];
#pragma unroll
  for (int i = 0; i < 8; ++i)
#pragma unroll
    for (int j = 0; j < 8; ++j) acc[i][j] = 0.f;

  float bv[8];
  if (to < 64) {
#pragma unroll
    for (int j = 0; j < 8; ++j) bv[j] = 0.f;
  } else {
    *reinterpret_cast<float4*>(&bv[0]) = *reinterpret_cast<const float4*>(bias + to - 64);
    *reinterpret_cast<float4*>(&bv[4]) = *reinterpret_cast<const float4*>(bias + to - 60);
  }

  const int lc = (t & 3) << 2;
  const int lr = t >> 2;

  for (int kk = 0; kk < 128; kk += BK) {
    __syncthreads();
#pragma unroll
    for (int p = 0; p < 2; ++p) {
      int rr = lr + p * 64;
      int row = n0 + rr;
      float4 va = make_float4(0.f, 0.f, 0.f, 0.f);
      if (row < N_NODES) {
        va = *reinterpret_cast<const float4*>(h + (size_t)row * 128 + kk + lc);
      }
      const float* wsrc = (rr < 64) ? (Wrel + (size_t)rr * 128)
                                    : (Wroot + (size_t)(rr - 64) * 128);
      float4 vw = *reinterpret_cast<const float4*>(wsrc + kk + lc);
      sA[(lc + 0) * LDSW + rr] = va.x;
      sA[(lc + 1) * LDSW + rr] = va.y;
      sA[(lc + 2) * LDSW + rr] = va.z;
      sA[(lc + 3) * LDSW + rr] = va.w;
      sW[(lc + 0) * LDSW + rr] = vw.x;
      sW[(lc + 1) * LDSW + rr] = vw.y;
      sW[(lc + 2) * LDSW + rr] = vw.z;
      sW[(lc + 3) * LDSW + rr] = vw.w;
    }
    __syncthreads();
#pragma unroll
    for (int k = 0; k < BK; ++k) {
      float av[8], wv[8];
      *reinterpret_cast<float4*>(&av[0]) = *reinterpret_cast<const float4*>(&sA[k * LDSW + tn]);
      *reinterpret_cast<float4*>(&av[4]) = *reinterpret_cast<const float4*>(&sA[k * LDSW + tn + 4]);
      *reinterpret_cast<float4*>(&wv[0]) = *reinterpret_cast<const float4*>(&sW[k * LDSW + to]);
      *reinterpret_cast<float4*>(&wv[4]) = *reinterpret_cast<const float4*>(&sW[k * LDSW + to + 4]);
#pragma unroll
      for (int i = 0; i < 8; ++i)
#pragma unroll
        for (int j = 0; j < 8; ++j)
          acc[i][j] = fmaf(av[i], wv[j], acc[i][j]);
    }
  }

#pragma unroll
  for (int i = 0; i < 8; ++i) {
    int row = n0 + tn + i;
    if (row < N_NODES) {
      float* dst = (to < 64) ? (t2 + (size_t)row * 64 + to)
                             : (out + (size_t)row * 64 + to - 64);
#pragma unroll
      for (int j = 0; j < 8; j += 4) {
        float4 o;
        o.x = acc[i][j + 0] + bv[j + 0];
        o.y = acc[i][j + 1] + bv[j + 1];
        o.z = acc[i][j + 2] + bv[j + 2];
        o.w = acc[i][j + 3] + bv[j + 3];
        *reinterpret_cast<float4*>(dst + j) = o;
      }
    }
  }
}

extern "C" void kernel_launch(void* const* d_in, const int* in_sizes, int n_in,
                              void* d_out, int out_size, void* d_ws, size_t ws_size,
                              hipStream_t stream) {
  const float* x = (const float*)d_in[0];
  const int* ei = (const int*)d_in[1];
  const float* W1rel = (const float*)d_in[2];
  const float* W1root = (const float*)d_in[3];
  const float* b1 = (const float*)d_in[4];
  const float* W2rel = (const float*)d_in[5];
  const float* W2root = (const float*)d_in[6];
  const float* b2 = (const float*)d_in[7];
  float* out = (float*)d_out;

  // workspace layout
  float* agg = (float*)d_ws;                          // 40000*128 f  (20.48 MB)
  float* h = agg + (size_t)N_NODES * 128;             // 40000*128 f  (20.48 MB)
  float* t2 = h + (size_t)N_NODES * 128;              // 40000*64  f  (10.24 MB)
  int* deg = (int*)(t2 + (size_t)N_NODES * 64);       // 40000 int
  int* offs = deg + N_NODES;                          // 40001 int
  int* cursor = offs + (N_NODES + 1);                 // 40000 int
  int* csr_src = cursor + N_NODES;                    // 640000 int

  // ---- CSR build (per call; ws is re-poisoned before every launch) ----
  hipMemsetAsync(deg, 0, (size_t)N_NODES * sizeof(int), stream);
  k_count<<<N_EDGES / 256, 256, 0, stream>>>(ei, deg);
  k_scan<<<1, 1024, 0, stream>>>(deg, offs, cursor);
  k_fill<<<N_EDGES / 256, 256, 0, stream>>>(ei, cursor, csr_src);

  // ---- layer 1: agg = gather-sum(x), h = relu(agg@W1rel.T + x@W1root.T + b1)
  k_gather128<<<N_NODES / 4, 256, 0, stream>>>(x, csr_src, offs, agg);
  int gblocks = (N_NODES + BM - 1) / BM;
  k_gemm1<<<gblocks, 256, 0, stream>>>(agg, x, W1rel, W1root, b1, h);

  // ---- layer 2 (transform-first): t2 = h@W2rel.T ; out = h@W2root.T + b2
  k_gemm2<<<gblocks, 256, 0, stream>>>(h, W2rel, W2root, b2, t2, out);
  k_gather64<<<N_NODES / 4, 256, 0, stream>>>(t2, csr_src, offs, out);
}

// Round 3
// 300.771 us; speedup vs baseline: 1.2462x; 1.2462x over previous
//
#include <hip/hip_runtime.h>

#define N_NODES 40000
#define N_EDGES 640000
// IN_CH = HID_CH = 128, OUT_CH = 64

constexpr int BM = 128;        // node tile (GEMM)
constexpr int BK = 16;         // k tile
constexpr int LDSW = BM + 4;   // padded LDS row stride (floats)

// ================= CSR build =================
// deg[dst]++ per edge
__global__ __launch_bounds__(256) void k_count(
    const int* __restrict__ ei, int* __restrict__ deg) {
  int e = blockIdx.x * 256 + threadIdx.x;   // grid covers exactly N_EDGES
  atomicAdd(&deg[ei[N_EDGES + e]], 1);
}

// ---- multi-block exclusive scan (A: local scan, B: block sums, C: add) ----
// A: block b scans deg[b*1024 .. b*1024+1024) ; 256 thr x 4 elems
__global__ __launch_bounds__(256) void k_scanA(
    const int* __restrict__ deg, int* __restrict__ local,
    int* __restrict__ bsum) {
  const int t = threadIdx.x;
  const int base = blockIdx.x * 1024 + t * 4;
  int v0 = 0, v1 = 0, v2 = 0, v3 = 0;
  if (base < N_NODES) {   // N_NODES % 4 == 0, so all-or-nothing per thread
    int4 v = *reinterpret_cast<const int4*>(deg + base);
    v0 = v.x; v1 = v.y; v2 = v.z; v3 = v.w;
  }
  const int tot = v0 + v1 + v2 + v3;
  const int lane = t & 63;
  int ws = tot;
#pragma unroll
  for (int off = 1; off < 64; off <<= 1) {
    int y = __shfl_up(ws, off, 64);
    if (lane >= off) ws += y;
  }
  __shared__ int wsum[4];
  if (lane == 63) wsum[t >> 6] = ws;
  __syncthreads();
  const int w = t >> 6;
  int wbase = 0;
#pragma unroll
  for (int i = 0; i < 4; ++i) wbase += (i < w) ? wsum[i] : 0;
  const int incl = wbase + ws;   // inclusive through this thread's 4 elems
  const int excl = incl - tot;   // exclusive prefix of this thread's chunk
  if (base < N_NODES) {
    int4 o;
    o.x = excl;
    o.y = excl + v0;
    o.z = excl + v0 + v1;
    o.w = excl + v0 + v1 + v2;
    *reinterpret_cast<int4*>(local + base) = o;
  }
  if (t == 255) bsum[blockIdx.x] = incl;  // block total
}

// B: one wave scans the 40 block sums -> exclusive bases
__global__ __launch_bounds__(64) void k_scanB(
    const int* __restrict__ bsum, int* __restrict__ bbase) {
  const int t = threadIdx.x;
  int v = (t < 40) ? bsum[t] : 0;
  int ws = v;
#pragma unroll
  for (int off = 1; off < 64; off <<= 1) {
    int y = __shfl_up(ws, off, 64);
    if (t >= off) ws += y;
  }
  if (t < 40) bbase[t] = ws - v;
}

// C: offs/cursor = local + bbase[block-of-1024]
__global__ __launch_bounds__(256) void k_scanC(
    const int* __restrict__ local, const int* __restrict__ bbase,
    int* __restrict__ offs, int* __restrict__ cursor) {
  int i = blockIdx.x * 256 + threadIdx.x;
  if (i < N_NODES) {
    int v = local[i] + bbase[i >> 10];
    offs[i] = v;
    cursor[i] = v;
  }
  if (i == 0) offs[N_NODES] = N_EDGES;  // every edge's dst is in range
}

// csr_src[cursor[dst]++] = src  (order within a node irrelevant for sum)
__global__ __launch_bounds__(256) void k_fill(
    const int* __restrict__ ei, int* __restrict__ cursor,
    int* __restrict__ csr_src) {
  int e = blockIdx.x * 256 + threadIdx.x;
  int dst = ei[N_EDGES + e];
  int idx = atomicAdd(&cursor[dst], 1);
  csr_src[idx] = ei[e];
}

// ================= gather aggregation =================
// one wave64 per node, 2 ch/lane: agg[n] = sum_{j->n} x[j]  (128 ch)
__global__ __launch_bounds__(256) void k_gather128(
    const float* __restrict__ x, const int* __restrict__ csr_src,
    const int* __restrict__ offs, float* __restrict__ agg) {
  int n = blockIdx.x * 4 + (threadIdx.x >> 6);
  n = __builtin_amdgcn_readfirstlane(n);   // wave-uniform -> scalar loads
  const int lane = threadIdx.x & 63;
  const int s = offs[n], e = offs[n + 1];
  float2 a0 = make_float2(0.f, 0.f), a1 = a0, a2 = a0, a3 = a0;
  int i = s;
  for (; i + 3 < e; i += 4) {
    int s0 = csr_src[i], s1 = csr_src[i + 1];
    int s2 = csr_src[i + 2], s3 = csr_src[i + 3];
    float2 v0 = *reinterpret_cast<const float2*>(x + (size_t)s0 * 128 + lane * 2);
    float2 v1 = *reinterpret_cast<const float2*>(x + (size_t)s1 * 128 + lane * 2);
    float2 v2 = *reinterpret_cast<const float2*>(x + (size_t)s2 * 128 + lane * 2);
    float2 v3 = *reinterpret_cast<const float2*>(x + (size_t)s3 * 128 + lane * 2);
    a0.x += v0.x; a0.y += v0.y;
    a1.x += v1.x; a1.y += v1.y;
    a2.x += v2.x; a2.y += v2.y;
    a3.x += v3.x; a3.y += v3.y;
  }
  for (; i < e; ++i) {
    int s0 = csr_src[i];
    float2 v0 = *reinterpret_cast<const float2*>(x + (size_t)s0 * 128 + lane * 2);
    a0.x += v0.x; a0.y += v0.y;
  }
  float2 r = make_float2(a0.x + a1.x + a2.x + a3.x,
                         a0.y + a1.y + a2.y + a3.y);
  *reinterpret_cast<float2*>(agg + (size_t)n * 128 + lane * 2) = r;
}

// one wave64 per node, 1 ch/lane: out[n] += sum_{j->n} t2[j]  (64 ch)
__global__ __launch_bounds__(256) void k_gather64(
    const float* __restrict__ t2, const int* __restrict__ csr_src,
    const int* __restrict__ offs, float* __restrict__ out) {
  int n = blockIdx.x * 4 + (threadIdx.x >> 6);
  n = __builtin_amdgcn_readfirstlane(n);
  const int lane = threadIdx.x & 63;
  const int s = offs[n], e = offs[n + 1];
  float a0 = 0.f, a1 = 0.f, a2 = 0.f, a3 = 0.f;
  int i = s;
  for (; i + 3 < e; i += 4) {
    int s0 = csr_src[i], s1 = csr_src[i + 1];
    int s2 = csr_src[i + 2], s3 = csr_src[i + 3];
    a0 += t2[(size_t)s0 * 64 + lane];
    a1 += t2[(size_t)s1 * 64 + lane];
    a2 += t2[(size_t)s2 * 64 + lane];
    a3 += t2[(size_t)s3 * 64 + lane];
  }
  for (; i < e; ++i) a0 += t2[(size_t)csr_src[i] * 64 + lane];
  out[(size_t)n * 64 + lane] += (a0 + a1) + (a2 + a3);
}

// ---------------- GEMM1: h = relu(agg @ W1rel.T + x @ W1root.T + b1) ----
__global__ __launch_bounds__(256) void k_gemm1(
    const float* __restrict__ agg, const float* __restrict__ x,
    const float* __restrict__ Wrel, const float* __restrict__ Wroot,
    const float* __restrict__ bias, float* __restrict__ h) {
  __shared__ float sAg[BK * LDSW];
  __shared__ float sAx[BK * LDSW];
  __shared__ float sWr[BK * LDSW];
  __shared__ float sWo[BK * LDSW];

  const int t = threadIdx.x;
  const int n0 = blockIdx.x * BM;
  const int tn = (t >> 4) << 3;   // node offset within tile
  const int to = (t & 15) << 3;   // out-channel offset

  float acc[8][8];
#pragma unroll
  for (int i = 0; i < 8; ++i)
#pragma unroll
    for (int j = 0; j < 8; ++j) acc[i][j] = 0.f;

  float bv[8];
  *reinterpret_cast<float4*>(&bv[0]) = *reinterpret_cast<const float4*>(bias + to);
  *reinterpret_cast<float4*>(&bv[4]) = *reinterpret_cast<const float4*>(bias + to + 4);

  const int lc = (t & 3) << 2;
  const int lr = t >> 2;

  for (int kk = 0; kk < 128; kk += BK) {
    __syncthreads();
#pragma unroll
    for (int p = 0; p < 2; ++p) {
      int rr = lr + p * 64;
      int row = n0 + rr;
      float4 va = make_float4(0.f, 0.f, 0.f, 0.f);
      float4 vx = va;
      if (row < N_NODES) {
        va = *reinterpret_cast<const float4*>(agg + (size_t)row * 128 + kk + lc);
        vx = *reinterpret_cast<const float4*>(x + (size_t)row * 128 + kk + lc);
      }
      float4 vr = *reinterpret_cast<const float4*>(Wrel + (size_t)rr * 128 + kk + lc);
      float4 vo = *reinterpret_cast<const float4*>(Wroot + (size_t)rr * 128 + kk + lc);
      sAg[(lc + 0) * LDSW + rr] = va.x;
      sAg[(lc + 1) * LDSW + rr] = va.y;
      sAg[(lc + 2) * LDSW + rr] = va.z;
      sAg[(lc + 3) * LDSW + rr] = va.w;
      sAx[(lc + 0) * LDSW + rr] = vx.x;
      sAx[(lc + 1) * LDSW + rr] = vx.y;
      sAx[(lc + 2) * LDSW + rr] = vx.z;
      sAx[(lc + 3) * LDSW + rr] = vx.w;
      sWr[(lc + 0) * LDSW + rr] = vr.x;
      sWr[(lc + 1) * LDSW + rr] = vr.y;
      sWr[(lc + 2) * LDSW + rr] = vr.z;
      sWr[(lc + 3) * LDSW + rr] = vr.w;
      sWo[(lc + 0) * LDSW + rr] = vo.x;
      sWo[(lc + 1) * LDSW + rr] = vo.y;
      sWo[(lc + 2) * LDSW + rr] = vo.z;
      sWo[(lc + 3) * LDSW + rr] = vo.w;
    }
    __syncthreads();
#pragma unroll
    for (int k = 0; k < BK; ++k) {
      float av[8], cv[8], rv[8], ov[8];
      *reinterpret_cast<float4*>(&av[0]) = *reinterpret_cast<const float4*>(&sAg[k * LDSW + tn]);
      *reinterpret_cast<float4*>(&av[4]) = *reinterpret_cast<const float4*>(&sAg[k * LDSW + tn + 4]);
      *reinterpret_cast<float4*>(&cv[0]) = *reinterpret_cast<const float4*>(&sAx[k * LDSW + tn]);
      *reinterpret_cast<float4*>(&cv[4]) = *reinterpret_cast<const float4*>(&sAx[k * LDSW + tn + 4]);
      *reinterpret_cast<float4*>(&rv[0]) = *reinterpret_cast<const float4*>(&sWr[k * LDSW + to]);
      *reinterpret_cast<float4*>(&rv[4]) = *reinterpret_cast<const float4*>(&sWr[k * LDSW + to + 4]);
      *reinterpret_cast<float4*>(&ov[0]) = *reinterpret_cast<const float4*>(&sWo[k * LDSW + to]);
      *reinterpret_cast<float4*>(&ov[4]) = *reinterpret_cast<const float4*>(&sWo[k * LDSW + to + 4]);
#pragma unroll
      for (int i = 0; i < 8; ++i)
#pragma unroll
        for (int j = 0; j < 8; ++j)
          acc[i][j] = fmaf(av[i], rv[j], fmaf(cv[i], ov[j], acc[i][j]));
    }
  }

#pragma unroll
  for (int i = 0; i < 8; ++i) {
    int row = n0 + tn + i;
    if (row < N_NODES) {
#pragma unroll
      for (int j = 0; j < 8; j += 4) {
        float4 o;
        o.x = fmaxf(acc[i][j + 0] + bv[j + 0], 0.f);
        o.y = fmaxf(acc[i][j + 1] + bv[j + 1], 0.f);
        o.z = fmaxf(acc[i][j + 2] + bv[j + 2], 0.f);
        o.w = fmaxf(acc[i][j + 3] + bv[j + 3], 0.f);
        *reinterpret_cast<float4*>(h + (size_t)row * 128 + to + j) = o;
      }
    }
  }
}

// ---------------- GEMM2: [t2 | out_init] = h @ [W2rel ; W2root].T (+b2) --
__global__ __launch_bounds__(256) void k_gemm2(
    const float* __restrict__ h, const float* __restrict__ Wrel,
    const float* __restrict__ Wroot, const float* __restrict__ bias,
    float* __restrict__ t2, float* __restrict__ out) {
  __shared__ float sA[BK * LDSW];
  __shared__ float sW[BK * LDSW];

  const int t = threadIdx.x;
  const int n0 = blockIdx.x * BM;
  const int tn = (t >> 4) << 3;
  const int to = (t & 15) << 3;

  float acc[8][8];
#pragma unroll
  for (int i = 0; i < 8; ++i)
#pragma unroll
    for (int j = 0; j < 8; ++j) acc[i][j] = 0.f;

  float bv[8];
  if (to < 64) {
#pragma unroll
    for (int j = 0; j < 8; ++j) bv[j] = 0.f;
  } else {
    *reinterpret_cast<float4*>(&bv[0]) = *reinterpret_cast<const float4*>(bias + to - 64);
    *reinterpret_cast<float4*>(&bv[4]) = *reinterpret_cast<const float4*>(bias + to - 60);
  }

  const int lc = (t & 3) << 2;
  const int lr = t >> 2;

  for (int kk = 0; kk < 128; kk += BK) {
    __syncthreads();
#pragma unroll
    for (int p = 0; p < 2; ++p) {
      int rr = lr + p * 64;
      int row = n0 + rr;
      float4 va = make_float4(0.f, 0.f, 0.f, 0.f);
      if (row < N_NODES) {
        va = *reinterpret_cast<const float4*>(h + (size_t)row * 128 + kk + lc);
      }
      const float* wsrc = (rr < 64) ? (Wrel + (size_t)rr * 128)
                                    : (Wroot + (size_t)(rr - 64) * 128);
      float4 vw = *reinterpret_cast<const float4*>(wsrc + kk + lc);
      sA[(lc + 0) * LDSW + rr] = va.x;
      sA[(lc + 1) * LDSW + rr] = va.y;
      sA[(lc + 2) * LDSW + rr] = va.z;
      sA[(lc + 3) * LDSW + rr] = va.w;
      sW[(lc + 0) * LDSW + rr] = vw.x;
      sW[(lc + 1) * LDSW + rr] = vw.y;
      sW[(lc + 2) * LDSW + rr] = vw.z;
      sW[(lc + 3) * LDSW + rr] = vw.w;
    }
    __syncthreads();
#pragma unroll
    for (int k = 0; k < BK; ++k) {
      float av[8], wv[8];
      *reinterpret_cast<float4*>(&av[0]) = *reinterpret_cast<const float4*>(&sA[k * LDSW + tn]);
      *reinterpret_cast<float4*>(&av[4]) = *reinterpret_cast<const float4*>(&sA[k * LDSW + tn + 4]);
      *reinterpret_cast<float4*>(&wv[0]) = *reinterpret_cast<const float4*>(&sW[k * LDSW + to]);
      *reinterpret_cast<float4*>(&wv[4]) = *reinterpret_cast<const float4*>(&sW[k * LDSW + to + 4]);
#pragma unroll
      for (int i = 0; i < 8; ++i)
#pragma unroll
        for (int j = 0; j < 8; ++j)
          acc[i][j] = fmaf(av[i], wv[j], acc[i][j]);
    }
  }

#pragma unroll
  for (int i = 0; i < 8; ++i) {
    int row = n0 + tn + i;
    if (row < N_NODES) {
      float* dst = (to < 64) ? (t2 + (size_t)row * 64 + to)
                             : (out + (size_t)row * 64 + to - 64);
#pragma unroll
      for (int j = 0; j < 8; j += 4) {
        float4 o;
        o.x = acc[i][j + 0] + bv[j + 0];
        o.y = acc[i][j + 1] + bv[j + 1];
        o.z = acc[i][j + 2] + bv[j + 2];
        o.w = acc[i][j + 3] + bv[j + 3];
        *reinterpret_cast<float4*>(dst + j) = o;
      }
    }
  }
}

extern "C" void kernel_launch(void* const* d_in, const int* in_sizes, int n_in,
                              void* d_out, int out_size, void* d_ws, size_t ws_size,
                              hipStream_t stream) {
  const float* x = (const float*)d_in[0];
  const int* ei = (const int*)d_in[1];
  const float* W1rel = (const float*)d_in[2];
  const float* W1root = (const float*)d_in[3];
  const float* b1 = (const float*)d_in[4];
  const float* W2rel = (const float*)d_in[5];
  const float* W2root = (const float*)d_in[6];
  const float* b2 = (const float*)d_in[7];
  float* out = (float*)d_out;

  // workspace layout
  float* agg = (float*)d_ws;                          // 40000*128 f  (20.48 MB)
  float* h = agg + (size_t)N_NODES * 128;             // 40000*128 f
  float* t2 = h + (size_t)N_NODES * 128;              // 40000*64  f
  int* deg = (int*)(t2 + (size_t)N_NODES * 64);       // 40000 int
  int* offs = deg + N_NODES;                          // 40001 int
  int* cursor = offs + (N_NODES + 1);                 // 40000 int
  int* csr_src = cursor + N_NODES;                    // 640000 int
  int* bsum = csr_src + N_EDGES;                      // 40 int
  int* bbase = bsum + 64;                             // 40 int
  // scan 'local' buffer aliases agg: dead before k_gather128 writes agg
  int* local = (int*)agg;                             // 40960 int

  // ---- CSR build (per call; ws is re-poisoned before every launch) ----
  hipMemsetAsync(deg, 0, (size_t)N_NODES * sizeof(int), stream);
  k_count<<<N_EDGES / 256, 256, 0, stream>>>(ei, deg);
  k_scanA<<<(N_NODES + 1023) / 1024, 256, 0, stream>>>(deg, local, bsum);
  k_scanB<<<1, 64, 0, stream>>>(bsum, bbase);
  k_scanC<<<(N_NODES + 255) / 256, 256, 0, stream>>>(local, bbase, offs, cursor);
  k_fill<<<N_EDGES / 256, 256, 0, stream>>>(ei, cursor, csr_src);

  // ---- layer 1: agg = gather-sum(x), h = relu(agg@W1rel.T + x@W1root.T + b1)
  k_gather128<<<N_NODES / 4, 256, 0, stream>>>(x, csr_src, offs, agg);
  int gblocks = (N_NODES + BM - 1) / BM;
  k_gemm1<<<gblocks, 256, 0, stream>>>(agg, x, W1rel, W1root, b1, h);

  // ---- layer 2 (transform-first): t2 = h@W2rel.T ; out = h@W2root.T + b2
  k_gemm2<<<gblocks, 256, 0, stream>>>(h, W2rel, W2root, b2, t2, out);
  k_gather64<<<N_NODES / 4, 256, 0, stream>>>(t2, csr_src, offs, out);
}

// Round 4
// 274.849 us; speedup vs baseline: 1.3637x; 1.0943x over previous
//
#include <hip/hip_runtime.h>

#define N_NODES 40000
#define N_EDGES 640000
// IN_CH = HID_CH = 128, OUT_CH = 64

constexpr int BK = 16;         // k tile
constexpr int ALDS = 64 + 4;   // A-tile LDS row stride (BM=64 + pad)
constexpr int WLDS = 128 + 4;  // W-tile LDS row stride (128 cols + pad)

// ================= CSR build =================
__global__ __launch_bounds__(256) void k_count(
    const int* __restrict__ ei, int* __restrict__ deg) {
  int e = blockIdx.x * 256 + threadIdx.x;   // grid covers exactly N_EDGES
  atomicAdd(&deg[ei[N_EDGES + e]], 1);
}

// A: block b scans deg[b*1024 .. b*1024+1024) ; 256 thr x 4 elems
__global__ __launch_bounds__(256) void k_scanA(
    const int* __restrict__ deg, int* __restrict__ local,
    int* __restrict__ bsum) {
  const int t = threadIdx.x;
  const int base = blockIdx.x * 1024 + t * 4;
  int v0 = 0, v1 = 0, v2 = 0, v3 = 0;
  if (base < N_NODES) {
    int4 v = *reinterpret_cast<const int4*>(deg + base);
    v0 = v.x; v1 = v.y; v2 = v.z; v3 = v.w;
  }
  const int tot = v0 + v1 + v2 + v3;
  const int lane = t & 63;
  int ws = tot;
#pragma unroll
  for (int off = 1; off < 64; off <<= 1) {
    int y = __shfl_up(ws, off, 64);
    if (lane >= off) ws += y;
  }
  __shared__ int wsum[4];
  if (lane == 63) wsum[t >> 6] = ws;
  __syncthreads();
  const int w = t >> 6;
  int wbase = 0;
#pragma unroll
  for (int i = 0; i < 4; ++i) wbase += (i < w) ? wsum[i] : 0;
  const int incl = wbase + ws;
  const int excl = incl - tot;
  if (base < N_NODES) {
    int4 o;
    o.x = excl;
    o.y = excl + v0;
    o.z = excl + v0 + v1;
    o.w = excl + v0 + v1 + v2;
    *reinterpret_cast<int4*>(local + base) = o;
  }
  if (t == 255) bsum[blockIdx.x] = incl;
}

__global__ __launch_bounds__(64) void k_scanB(
    const int* __restrict__ bsum, int* __restrict__ bbase) {
  const int t = threadIdx.x;
  int v = (t < 40) ? bsum[t] : 0;
  int ws = v;
#pragma unroll
  for (int off = 1; off < 64; off <<= 1) {
    int y = __shfl_up(ws, off, 64);
    if (t >= off) ws += y;
  }
  if (t < 40) bbase[t] = ws - v;
}

__global__ __launch_bounds__(256) void k_scanC(
    const int* __restrict__ local, const int* __restrict__ bbase,
    int* __restrict__ offs, int* __restrict__ cursor) {
  int i = blockIdx.x * 256 + threadIdx.x;
  if (i < N_NODES) {
    int v = local[i] + bbase[i >> 10];
    offs[i] = v;
    cursor[i] = v;
  }
  if (i == 0) offs[N_NODES] = N_EDGES;
}

__global__ __launch_bounds__(256) void k_fill(
    const int* __restrict__ ei, int* __restrict__ cursor,
    int* __restrict__ csr_src) {
  int e = blockIdx.x * 256 + threadIdx.x;
  int dst = ei[N_EDGES + e];
  int idx = atomicAdd(&cursor[dst], 1);
  csr_src[idx] = ei[e];
}

// ================= gather aggregation =================
__global__ __launch_bounds__(256) void k_gather128(
    const float* __restrict__ x, const int* __restrict__ csr_src,
    const int* __restrict__ offs, float* __restrict__ agg) {
  int n = blockIdx.x * 4 + (threadIdx.x >> 6);
  n = __builtin_amdgcn_readfirstlane(n);
  const int lane = threadIdx.x & 63;
  const int s = offs[n], e = offs[n + 1];
  float2 a0 = make_float2(0.f, 0.f), a1 = a0, a2 = a0, a3 = a0;
  int i = s;
  for (; i + 3 < e; i += 4) {
    int s0 = csr_src[i], s1 = csr_src[i + 1];
    int s2 = csr_src[i + 2], s3 = csr_src[i + 3];
    float2 v0 = *reinterpret_cast<const float2*>(x + (size_t)s0 * 128 + lane * 2);
    float2 v1 = *reinterpret_cast<const float2*>(x + (size_t)s1 * 128 + lane * 2);
    float2 v2 = *reinterpret_cast<const float2*>(x + (size_t)s2 * 128 + lane * 2);
    float2 v3 = *reinterpret_cast<const float2*>(x + (size_t)s3 * 128 + lane * 2);
    a0.x += v0.x; a0.y += v0.y;
    a1.x += v1.x; a1.y += v1.y;
    a2.x += v2.x; a2.y += v2.y;
    a3.x += v3.x; a3.y += v3.y;
  }
  for (; i < e; ++i) {
    int s0 = csr_src[i];
    float2 v0 = *reinterpret_cast<const float2*>(x + (size_t)s0 * 128 + lane * 2);
    a0.x += v0.x; a0.y += v0.y;
  }
  float2 r = make_float2(a0.x + a1.x + a2.x + a3.x,
                         a0.y + a1.y + a2.y + a3.y);
  *reinterpret_cast<float2*>(agg + (size_t)n * 128 + lane * 2) = r;
}

__global__ __launch_bounds__(256) void k_gather64(
    const float* __restrict__ t2, const int* __restrict__ csr_src,
    const int* __restrict__ offs, float* __restrict__ out) {
  int n = blockIdx.x * 4 + (threadIdx.x >> 6);
  n = __builtin_amdgcn_readfirstlane(n);
  const int lane = threadIdx.x & 63;
  const int s = offs[n], e = offs[n + 1];
  float a0 = 0.f, a1 = 0.f, a2 = 0.f, a3 = 0.f;
  int i = s;
  for (; i + 3 < e; i += 4) {
    int s0 = csr_src[i], s1 = csr_src[i + 1];
    int s2 = csr_src[i + 2], s3 = csr_src[i + 3];
    a0 += t2[(size_t)s0 * 64 + lane];
    a1 += t2[(size_t)s1 * 64 + lane];
    a2 += t2[(size_t)s2 * 64 + lane];
    a3 += t2[(size_t)s3 * 64 + lane];
  }
  for (; i < e; ++i) a0 += t2[(size_t)csr_src[i] * 64 + lane];
  out[(size_t)n * 64 + lane] += (a0 + a1) + (a2 + a3);
}

// ---------------- GEMM1: h = relu(agg @ W1rel.T + x @ W1root.T + b1) ----
// BM=64 rows/block, 128 out-ch; 256 thr; micro-tile 4 rows x (4+4) cols.
// 40000 = 625 * 64 exactly -> no row guards.
__global__ __launch_bounds__(256) void k_gemm1(
    const float* __restrict__ agg, const float* __restrict__ x,
    const float* __restrict__ Wrel, const float* __restrict__ Wroot,
    const float* __restrict__ bias, float* __restrict__ h) {
  __shared__ float sAg[BK * ALDS];
  __shared__ float sAx[BK * ALDS];
  __shared__ float sWr[BK * WLDS];
  __shared__ float sWo[BK * WLDS];

  const int t = threadIdx.x;
  const int n0 = blockIdx.x * 64;
  const int r4 = (t >> 4) << 2;   // row offset 0..60
  const int c4 = (t & 15) << 2;   // col offset 0..60 (and +64)

  // loader indices
  const int lrow = t & 63;        // A: row 0..63
  const int lkc = t >> 6;         // A: k-chunk 0..3 (4 floats each)
  const int wcol = t & 127;       // W: col 0..127
  const int wh = t >> 7;          // W: k-half 0..1 (8 floats each)

  float acc[4][8];
#pragma unroll
  for (int i = 0; i < 4; ++i)
#pragma unroll
    for (int j = 0; j < 8; ++j) acc[i][j] = 0.f;

  for (int kk = 0; kk < 128; kk += BK) {
    __syncthreads();
    {
      float4 va = *reinterpret_cast<const float4*>(
          agg + (size_t)(n0 + lrow) * 128 + kk + lkc * 4);
      float4 vx = *reinterpret_cast<const float4*>(
          x + (size_t)(n0 + lrow) * 128 + kk + lkc * 4);
      sAg[(lkc * 4 + 0) * ALDS + lrow] = va.x;
      sAg[(lkc * 4 + 1) * ALDS + lrow] = va.y;
      sAg[(lkc * 4 + 2) * ALDS + lrow] = va.z;
      sAg[(lkc * 4 + 3) * ALDS + lrow] = va.w;
      sAx[(lkc * 4 + 0) * ALDS + lrow] = vx.x;
      sAx[(lkc * 4 + 1) * ALDS + lrow] = vx.y;
      sAx[(lkc * 4 + 2) * ALDS + lrow] = vx.z;
      sAx[(lkc * 4 + 3) * ALDS + lrow] = vx.w;
#pragma unroll
      for (int q = 0; q < 2; ++q) {
        float4 vr = *reinterpret_cast<const float4*>(
            Wrel + (size_t)wcol * 128 + kk + wh * 8 + q * 4);
        float4 vo = *reinterpret_cast<const float4*>(
            Wroot + (size_t)wcol * 128 + kk + wh * 8 + q * 4);
        sWr[(wh * 8 + q * 4 + 0) * WLDS + wcol] = vr.x;
        sWr[(wh * 8 + q * 4 + 1) * WLDS + wcol] = vr.y;
        sWr[(wh * 8 + q * 4 + 2) * WLDS + wcol] = vr.z;
        sWr[(wh * 8 + q * 4 + 3) * WLDS + wcol] = vr.w;
        sWo[(wh * 8 + q * 4 + 0) * WLDS + wcol] = vo.x;
        sWo[(wh * 8 + q * 4 + 1) * WLDS + wcol] = vo.y;
        sWo[(wh * 8 + q * 4 + 2) * WLDS + wcol] = vo.z;
        sWo[(wh * 8 + q * 4 + 3) * WLDS + wcol] = vo.w;
      }
    }
    __syncthreads();
#pragma unroll
    for (int k = 0; k < BK; ++k) {
      float av[4], cv[4], rv[8], ov[8];
      *reinterpret_cast<float4*>(&av[0]) =
          *reinterpret_cast<const float4*>(&sAg[k * ALDS + r4]);
      *reinterpret_cast<float4*>(&cv[0]) =
          *reinterpret_cast<const float4*>(&sAx[k * ALDS + r4]);
      *reinterpret_cast<float4*>(&rv[0]) =
          *reinterpret_cast<const float4*>(&sWr[k * WLDS + c4]);
      *reinterpret_cast<float4*>(&rv[4]) =
          *reinterpret_cast<const float4*>(&sWr[k * WLDS + 64 + c4]);
      *reinterpret_cast<float4*>(&ov[0]) =
          *reinterpret_cast<const float4*>(&sWo[k * WLDS + c4]);
      *reinterpret_cast<float4*>(&ov[4]) =
          *reinterpret_cast<const float4*>(&sWo[k * WLDS + 64 + c4]);
#pragma unroll
      for (int i = 0; i < 4; ++i)
#pragma unroll
        for (int j = 0; j < 8; ++j)
          acc[i][j] = fmaf(av[i], rv[j], fmaf(cv[i], ov[j], acc[i][j]));
    }
  }

  float bv[8];
  *reinterpret_cast<float4*>(&bv[0]) =
      *reinterpret_cast<const float4*>(bias + c4);
  *reinterpret_cast<float4*>(&bv[4]) =
      *reinterpret_cast<const float4*>(bias + 64 + c4);
#pragma unroll
  for (int i = 0; i < 4; ++i) {
    const size_t row = (size_t)(n0 + r4 + i) * 128;
    float4 o0, o1;
    o0.x = fmaxf(acc[i][0] + bv[0], 0.f);
    o0.y = fmaxf(acc[i][1] + bv[1], 0.f);
    o0.z = fmaxf(acc[i][2] + bv[2], 0.f);
    o0.w = fmaxf(acc[i][3] + bv[3], 0.f);
    o1.x = fmaxf(acc[i][4] + bv[4], 0.f);
    o1.y = fmaxf(acc[i][5] + bv[5], 0.f);
    o1.z = fmaxf(acc[i][6] + bv[6], 0.f);
    o1.w = fmaxf(acc[i][7] + bv[7], 0.f);
    *reinterpret_cast<float4*>(h + row + c4) = o0;
    *reinterpret_cast<float4*>(h + row + 64 + c4) = o1;
  }
}

// ---------------- GEMM2: [t2 | out_init] = h @ [W2rel ; W2root].T (+b2) --
// stacked 128 out-cols: 0..63 -> t2 (no bias), 64..127 -> out (with b2)
__global__ __launch_bounds__(256) void k_gemm2(
    const float* __restrict__ h, const float* __restrict__ Wrel,
    const float* __restrict__ Wroot, const float* __restrict__ bias,
    float* __restrict__ t2, float* __restrict__ out) {
  __shared__ float sA[BK * ALDS];
  __shared__ float sW[BK * WLDS];

  const int t = threadIdx.x;
  const int n0 = blockIdx.x * 64;
  const int r4 = (t >> 4) << 2;
  const int c4 = (t & 15) << 2;

  const int lrow = t & 63;
  const int lkc = t >> 6;
  const int wcol = t & 127;
  const int wh = t >> 7;
  const float* wsrc = (wcol < 64) ? (Wrel + (size_t)wcol * 128)
                                  : (Wroot + (size_t)(wcol - 64) * 128);

  float acc[4][8];
#pragma unroll
  for (int i = 0; i < 4; ++i)
#pragma unroll
    for (int j = 0; j < 8; ++j) acc[i][j] = 0.f;

  for (int kk = 0; kk < 128; kk += BK) {
    __syncthreads();
    {
      float4 va = *reinterpret_cast<const float4*>(
          h + (size_t)(n0 + lrow) * 128 + kk + lkc * 4);
      sA[(lkc * 4 + 0) * ALDS + lrow] = va.x;
      sA[(lkc * 4 + 1) * ALDS + lrow] = va.y;
      sA[(lkc * 4 + 2) * ALDS + lrow] = va.z;
      sA[(lkc * 4 + 3) * ALDS + lrow] = va.w;
#pragma unroll
      for (int q = 0; q < 2; ++q) {
        float4 vw = *reinterpret_cast<const float4*>(wsrc + kk + wh * 8 + q * 4);
        sW[(wh * 8 + q * 4 + 0) * WLDS + wcol] = vw.x;
        sW[(wh * 8 + q * 4 + 1) * WLDS + wcol] = vw.y;
        sW[(wh * 8 + q * 4 + 2) * WLDS + wcol] = vw.z;
        sW[(wh * 8 + q * 4 + 3) * WLDS + wcol] = vw.w;
      }
    }
    __syncthreads();
#pragma unroll
    for (int k = 0; k < BK; ++k) {
      float av[4], wv[8];
      *reinterpret_cast<float4*>(&av[0]) =
          *reinterpret_cast<const float4*>(&sA[k * ALDS + r4]);
      *reinterpret_cast<float4*>(&wv[0]) =
          *reinterpret_cast<const float4*>(&sW[k * WLDS + c4]);
      *reinterpret_cast<float4*>(&wv[4]) =
          *reinterpret_cast<const float4*>(&sW[k * WLDS + 64 + c4]);
#pragma unroll
      for (int i = 0; i < 4; ++i)
#pragma unroll
        for (int j = 0; j < 8; ++j)
          acc[i][j] = fmaf(av[i], wv[j], acc[i][j]);
    }
  }

  float bv[4];
  *reinterpret_cast<float4*>(&bv[0]) =
      *reinterpret_cast<const float4*>(bias + c4);   // cols 64+c4 -> b2[c4]
#pragma unroll
  for (int i = 0; i < 4; ++i) {
    const size_t row = (size_t)(n0 + r4 + i) * 64;
    float4 o0, o1;
    o0.x = acc[i][0]; o0.y = acc[i][1]; o0.z = acc[i][2]; o0.w = acc[i][3];
    o1.x = acc[i][4] + bv[0];
    o1.y = acc[i][5] + bv[1];
    o1.z = acc[i][6] + bv[2];
    o1.w = acc[i][7] + bv[3];
    *reinterpret_cast<float4*>(t2 + row + c4) = o0;   // cols 0..63
    *reinterpret_cast<float4*>(out + row + c4) = o1;  // cols 64..127 -> out
  }
}

extern "C" void kernel_launch(void* const* d_in, const int* in_sizes, int n_in,
                              void* d_out, int out_size, void* d_ws, size_t ws_size,
                              hipStream_t stream) {
  const float* x = (const float*)d_in[0];
  const int* ei = (const int*)d_in[1];
  const float* W1rel = (const float*)d_in[2];
  const float* W1root = (const float*)d_in[3];
  const float* b1 = (const float*)d_in[4];
  const float* W2rel = (const float*)d_in[5];
  const float* W2root = (const float*)d_in[6];
  const float* b2 = (const float*)d_in[7];
  float* out = (float*)d_out;

  // workspace layout
  float* agg = (float*)d_ws;                          // 40000*128 f
  float* h = agg + (size_t)N_NODES * 128;             // 40000*128 f
  float* t2 = h + (size_t)N_NODES * 128;              // 40000*64  f
  int* deg = (int*)(t2 + (size_t)N_NODES * 64);       // 40000 int
  int* offs = deg + N_NODES;                          // 40001 int
  int* cursor = offs + (N_NODES + 1);                 // 40000 int
  int* csr_src = cursor + N_NODES;                    // 640000 int
  int* bsum = csr_src + N_EDGES;                      // 40 int
  int* bbase = bsum + 64;                             // 40 int
  int* local = (int*)agg;                             // aliases agg (dead)

  // ---- CSR build ----
  hipMemsetAsync(deg, 0, (size_t)N_NODES * sizeof(int), stream);
  k_count<<<N_EDGES / 256, 256, 0, stream>>>(ei, deg);
  k_scanA<<<(N_NODES + 1023) / 1024, 256, 0, stream>>>(deg, local, bsum);
  k_scanB<<<1, 64, 0, stream>>>(bsum, bbase);
  k_scanC<<<(N_NODES + 255) / 256, 256, 0, stream>>>(local, bbase, offs, cursor);
  k_fill<<<N_EDGES / 256, 256, 0, stream>>>(ei, cursor, csr_src);

  // ---- layer 1 ----
  k_gather128<<<N_NODES / 4, 256, 0, stream>>>(x, csr_src, offs, agg);
  k_gemm1<<<N_NODES / 64, 256, 0, stream>>>(agg, x, W1rel, W1root, b1, h);

  // ---- layer 2 (transform-first) ----
  k_gemm2<<<N_NODES / 64, 256, 0, stream>>>(h, W2rel, W2root, b2, t2, out);
  k_gather64<<<N_NODES / 4, 256, 0, stream>>>(t2, csr_src, offs, out);
}